// Round 2
// baseline (317.454 us; speedup 1.0000x reference)
//
#include <hip/hip_runtime.h>
#include <math.h>

#define DIMK 2048
#define NSEQ 4096
#define NT (DIMK / 64)  // 32 K-tiles of BK=64

typedef short bf16x8 __attribute__((ext_vector_type(8)));
typedef float f32x4 __attribute__((ext_vector_type(4)));
typedef unsigned short u16;

__device__ __forceinline__ u16 f32_to_bf16(float f) {
  unsigned u = __float_as_uint(f);
  u += 0x7fffu + ((u >> 16) & 1u);  // round-to-nearest-even
  return (u16)(u >> 16);
}

__device__ __forceinline__ void async16(const u16* g, u16* l) {
  __builtin_amdgcn_global_load_lds(
      (const __attribute__((address_space(1))) unsigned int*)g,
      (__attribute__((address_space(3))) unsigned int*)l,
      16, 0, 0);
}

// -------- fused fp32 -> bf16 cast for x, Wq, Wk (one launch) --------
__global__ __launch_bounds__(256) void cast3_f32_bf16(
    const float* __restrict__ x, const float* __restrict__ wq,
    const float* __restrict__ wk, u16* __restrict__ xb,
    u16* __restrict__ wqb, u16* __restrict__ wkb) {
  const int xN4 = NSEQ * DIMK / 4;
  const int wN4 = DIMK * DIMK / 4;
  int i = blockIdx.x * 256 + threadIdx.x;
  const float* src;
  u16* dst;
  int j;
  if (i < xN4) { src = x; dst = xb; j = i; }
  else if (i < xN4 + wN4) { src = wq; dst = wqb; j = i - xN4; }
  else { src = wk; dst = wkb; j = i - xN4 - wN4; }
  float4 v = ((const float4*)src)[j];
  ushort4 o;
  o.x = f32_to_bf16(v.x);
  o.y = f32_to_bf16(v.y);
  o.z = f32_to_bf16(v.z);
  o.w = f32_to_bf16(v.w);
  ((ushort4*)dst)[j] = o;
}

// ===================== 256x256 pipelined 4-phase NT GEMM =====================
// BM=BN=256, BK=64, 512 threads = 8 waves (2 M-groups x 4 N-groups).
// Per wave: 128x64 output = acc[8][4] f32x4; quadrants:
//   P1: acc[0..3][0..1] = a1 x b01    P2: acc[0..3][2..3] = a1 x b23
//   P3: acc[4..7][0..1] = a2 x b01    P4: acc[4..7][2..3] = a2 x b23
// KEY CHANGE vs round 1: ds_reads are issued ONE PHASE AHEAD of their
// consuming MFMA cluster, and there is NO explicit lgkmcnt(0) anywhere —
// the compiler emits precise counted lgkmcnt waits per operand group, so
// the post-barrier full-drain stall (the round-1 37%-MfmaUtil cap) is gone.
//   P1: issue b23 reads      | MFMA P1 | stage A-bot(t+1->nxt) | BAR
//   P2: issue a2 reads       | MFMA P2 |                       | BAR
//   P3:                      | MFMA P3 | stage B(t+2->cur)     | BAR
//   P4: stage A-top(t+2->cur); vmcnt(6); BAR; sched_barrier;
//       issue a1',b01' reads (next buf) | MFMA P4 | BAR
// Liveness (read-retire point -> earliest overwrite): b01 retires P1,
// b23 retires P2 -> B staged P3; a1 retires P2, a2 retires P3 -> A-top
// staged P4; A-bot(nxt) last read tile t-1 P3 -> staged t.P1. vmcnt(6) at
// P4 leaves exactly the 3 t+2 half-tile stages in flight; buffer nxt is
// complete at the post-vmcnt barrier, so next-tile reads follow it.

#define VM6 asm volatile("s_waitcnt vmcnt(6)" ::: "memory")
#define VM0 asm volatile("s_waitcnt vmcnt(0)" ::: "memory")
#define BAR __builtin_amdgcn_s_barrier()
#define SCHED0 __builtin_amdgcn_sched_barrier(0)
#define PRIO1 __builtin_amdgcn_s_setprio(1)
#define PRIO0 __builtin_amdgcn_s_setprio(0)
#define NOOP ((void)0)

#define ISSUE(g, t_, reg)                                     \
  do {                                                        \
    const u16* _gp = (g) + (size_t)(t_) * 64 + stg_goff;      \
    async16(_gp, (reg) + tid * 8);                            \
    async16(_gp + (size_t)64 * DIMK, (reg) + 4096 + tid * 8); \
  } while (0)

// ---- fragment read helpers (all indices compile-time after unroll) ----
#define RD_A1(bi)                                                   \
  _Pragma("unroll") for (int i = 0; i < 4; ++i) {                   \
    a1[i][0] = *(const bf16x8*)&rdA[bi][(i * 16 + fr) * 64 + c0];   \
    a1[i][1] = *(const bf16x8*)&rdA[bi][(i * 16 + fr) * 64 + c1];   \
  }
#define RD_A2(bi)                                                         \
  _Pragma("unroll") for (int i = 0; i < 4; ++i) {                         \
    a2[i][0] = *(const bf16x8*)&rdA[bi][((i + 4) * 16 + fr) * 64 + c0];   \
    a2[i][1] = *(const bf16x8*)&rdA[bi][((i + 4) * 16 + fr) * 64 + c1];   \
  }
#define RD_B01(bi)                                                  \
  _Pragma("unroll") for (int j = 0; j < 2; ++j) {                   \
    b01[j][0] = *(const bf16x8*)&rdB[bi][(j * 16 + fr) * 64 + c0];  \
    b01[j][1] = *(const bf16x8*)&rdB[bi][(j * 16 + fr) * 64 + c1];  \
  }
#define RD_B23(bi)                                                        \
  _Pragma("unroll") for (int j = 0; j < 2; ++j) {                         \
    b23[j][0] = *(const bf16x8*)&rdB[bi][((j + 2) * 16 + fr) * 64 + c0];  \
    b23[j][1] = *(const bf16x8*)&rdB[bi][((j + 2) * 16 + fr) * 64 + c1];  \
  }

#define MFQ(i, j, Aa, ai, Bb, bj)                                           \
  acc[i][j] = __builtin_amdgcn_mfma_f32_16x16x32_bf16(Aa[ai][0], Bb[bj][0], \
                                                      acc[i][j], 0, 0, 0);  \
  acc[i][j] = __builtin_amdgcn_mfma_f32_16x16x32_bf16(Aa[ai][1], Bb[bj][1], \
                                                      acc[i][j], 0, 0, 0);

#define CL_P1                                                   \
  MFQ(0, 0, a1, 0, b01, 0) MFQ(0, 1, a1, 0, b01, 1)             \
  MFQ(1, 0, a1, 1, b01, 0) MFQ(1, 1, a1, 1, b01, 1)             \
  MFQ(2, 0, a1, 2, b01, 0) MFQ(2, 1, a1, 2, b01, 1)             \
  MFQ(3, 0, a1, 3, b01, 0) MFQ(3, 1, a1, 3, b01, 1)
#define CL_P2                                                   \
  MFQ(0, 2, a1, 0, b23, 0) MFQ(0, 3, a1, 0, b23, 1)             \
  MFQ(1, 2, a1, 1, b23, 0) MFQ(1, 3, a1, 1, b23, 1)             \
  MFQ(2, 2, a1, 2, b23, 0) MFQ(2, 3, a1, 2, b23, 1)             \
  MFQ(3, 2, a1, 3, b23, 0) MFQ(3, 3, a1, 3, b23, 1)
#define CL_P3                                                   \
  MFQ(4, 0, a2, 0, b01, 0) MFQ(4, 1, a2, 0, b01, 1)             \
  MFQ(5, 0, a2, 1, b01, 0) MFQ(5, 1, a2, 1, b01, 1)             \
  MFQ(6, 0, a2, 2, b01, 0) MFQ(6, 1, a2, 2, b01, 1)             \
  MFQ(7, 0, a2, 3, b01, 0) MFQ(7, 1, a2, 3, b01, 1)
#define CL_P4                                                   \
  MFQ(4, 2, a2, 0, b23, 0) MFQ(4, 3, a2, 0, b23, 1)             \
  MFQ(5, 2, a2, 1, b23, 0) MFQ(5, 3, a2, 1, b23, 1)             \
  MFQ(6, 2, a2, 2, b23, 0) MFQ(6, 3, a2, 2, b23, 1)             \
  MFQ(7, 2, a2, 3, b23, 0) MFQ(7, 3, a2, 3, b23, 1)

#define TILE(bi, SP1, SP3A, SP3B, SP4, VMW) \
  do {                                      \
    /* P1 */                                \
    RD_B23(bi);                             \
    SP1;                                    \
    PRIO1; CL_P1; PRIO0;                    \
    BAR;                                    \
    /* P2 */                                \
    RD_A2(bi);                              \
    PRIO1; CL_P2; PRIO0;                    \
    BAR;                                    \
    /* P3 */                                \
    SP3A;                                   \
    SP3B;                                   \
    PRIO1; CL_P3; PRIO0;                    \
    BAR;                                    \
    /* P4 */                                \
    SP4;                                    \
    VMW;                                    \
    BAR;                                    \
    SCHED0;                                 \
    RD_A1((bi) ^ 1);                        \
    RD_B01((bi) ^ 1);                       \
    PRIO1; CL_P4; PRIO0;                    \
    BAR;                                    \
  } while (0)

#define TILE_LAST(bi)        \
  do {                       \
    RD_B23(bi);              \
    PRIO1; CL_P1; PRIO0;     \
    BAR;                     \
    RD_A2(bi);               \
    PRIO1; CL_P2; PRIO0;     \
    BAR;                     \
    PRIO1; CL_P3; PRIO0;     \
    BAR;                     \
    PRIO1; CL_P4; PRIO0;     \
  } while (0)

__device__ __forceinline__ void mainloop256(
    const u16* __restrict__ A, const u16* __restrict__ B, int rowBase,
    int colBase, u16 (*lds)[2][2][8192], f32x4 acc[8][4]) {
  const int tid = threadIdx.x;
  const int lane = tid & 63;
  const int wid = tid >> 6;
  const int wmg = wid >> 2;  // 0,1 : which 128-row half of A-tile
  const int wng = wid & 3;   // 0..3: which 64-row strip of B-tile
  const int fr = lane & 15;
  const int kq = lane >> 4;

  // staging: thread covers row (tid>>3), phys chunk (tid&7); pre-swizzled
  // global source chunk = (tid&7) ^ (row&7)  (linear LDS dest, swizzled src).
  const int stg_goff =
      (tid >> 3) * DIMK + (((tid & 7) ^ ((tid >> 3) & 7)) * 8);
  // frag-read phys chunk offsets (elements) for k-step 0 / 1
  const int c0 = (kq ^ (fr & 7)) * 8;
  const int c1 = ((4 + kq) ^ (fr & 7)) * 8;

  const u16* gA0 = A + (size_t)rowBase * DIMK;
  const u16* gA1 = gA0 + (size_t)128 * DIMK;
  const u16* gB0 = B + (size_t)colBase * DIMK;
  const u16* gB1 = gB0 + (size_t)128 * DIMK;

  u16* sA0[2] = {&lds[0][0][0][0], &lds[1][0][0][0]};
  u16* sA1[2] = {&lds[0][0][1][0], &lds[1][0][1][0]};
  u16* sB0[2] = {&lds[0][1][0][0], &lds[1][1][0][0]};
  u16* sB1[2] = {&lds[0][1][1][0], &lds[1][1][1][0]};

  const u16* rdA[2] = {&lds[0][0][wmg][0], &lds[1][0][wmg][0]};
  const u16* rdB[2] = {&lds[0][1][wng >> 1][(wng & 1) * 4096],
                       &lds[1][1][wng >> 1][(wng & 1) * 4096]};

  bf16x8 a1[4][2], a2[4][2], b01[2][2], b23[2][2];

  // ---- prologue: tile0 fully + 3/4 of tile1 (A-bot comes at tile0.P1) ----
  ISSUE(gB0, 0, sB0[0]);
  ISSUE(gB1, 0, sB1[0]);
  ISSUE(gA0, 0, sA0[0]);
  ISSUE(gA1, 0, sA1[0]);
  ISSUE(gB0, 1, sB0[1]);
  ISSUE(gB1, 1, sB1[1]);
  ISSUE(gA0, 1, sA0[1]);
  VM6;  // drain tile0's 8 items; tile1's 6 stay in flight
  BAR;
  SCHED0;
  RD_A1(0);
  RD_B01(0);

#pragma unroll 1
  for (int t = 0; t < NT - 2; t += 2) {
    TILE(0,
         ISSUE(gA1, t + 1, sA1[1]),   // P1: finish tile t+1 (other buf)
         ISSUE(gB0, t + 2, sB0[0]),   // P3: B-top dead since P1 retire
         ISSUE(gB1, t + 2, sB1[0]),   // P3: B-bot
         ISSUE(gA0, t + 2, sA0[0]),   // P4: A-top dead since P3 retire
         VM6);
    TILE(1,
         ISSUE(gA1, t + 2, sA1[0]),
         ISSUE(gB0, t + 3, sB0[1]),
         ISSUE(gB1, t + 3, sB1[1]),
         ISSUE(gA0, t + 3, sA0[1]),
         VM6);
  }
  // tile NT-2 (buf0): finish staging tile NT-1, full drain, then last tile
  TILE(0, ISSUE(gA1, NT - 1, sA1[1]), NOOP, NOOP, NOOP, VM0);
  TILE_LAST(1);
}

// -------- GEMM1: Q = x Wq^T + bq ; K = x Wk^T + bk  (z selects) --------
__global__ __launch_bounds__(512) void gemm_qk(
    const u16* __restrict__ X, const u16* __restrict__ Wq,
    const u16* __restrict__ Wk, const float* __restrict__ bq,
    const float* __restrict__ bk, u16* __restrict__ Qo, u16* __restrict__ Ko) {
  __shared__ u16 lds[2][2][2][8192];  // 128 KiB
  const u16* Bmat = blockIdx.z ? Wk : Wq;
  const float* bias = blockIdx.z ? bk : bq;
  u16* Out = blockIdx.z ? Ko : Qo;
  const int rowBase = blockIdx.y * 256;
  const int colBase = blockIdx.x * 256;

  f32x4 acc[8][4] = {};
  mainloop256(X, Bmat, rowBase, colBase, lds, acc);

  const int tid = threadIdx.x;
  const int lane = tid & 63;
  const int wid = tid >> 6;
  const int wmg = wid >> 2;
  const int wng = wid & 3;
  const int fr = lane & 15;
  const int rq = (lane >> 4) * 4;
  const int r0 = rowBase + wmg * 128;
  const int cb = colBase + wng * 64;
#pragma unroll
  for (int j = 0; j < 4; ++j) {
    const int col = cb + j * 16 + fr;
    const float bv = bias[col];
#pragma unroll
    for (int i = 0; i < 8; ++i) {
#pragma unroll
      for (int r = 0; r < 4; ++r) {
        const int row = r0 + i * 16 + rq + r;
        Out[(size_t)row * DIMK + col] = f32_to_bf16(acc[i][j][r] + bv);
      }
    }
  }
}

// -------- GEMM2: scores = scale * Q K^T  (bf16 in, fp32 out) --------
__global__ __launch_bounds__(512) void gemm_scores(
    const u16* __restrict__ Qi, const u16* __restrict__ Ki,
    float* __restrict__ out, float scale) {
  __shared__ u16 lds[2][2][2][8192];
  const int rowBase = blockIdx.y * 256;
  const int colBase = blockIdx.x * 256;

  f32x4 acc[8][4] = {};
  mainloop256(Qi, Ki, rowBase, colBase, lds, acc);

  const int tid = threadIdx.x;
  const int lane = tid & 63;
  const int wid = tid >> 6;
  const int wmg = wid >> 2;
  const int wng = wid & 3;
  const int fr = lane & 15;
  const int rq = (lane >> 4) * 4;
  const int r0 = rowBase + wmg * 128;
  const int cb = colBase + wng * 64;
#pragma unroll
  for (int j = 0; j < 4; ++j) {
    const int col = cb + j * 16 + fr;
#pragma unroll
    for (int i = 0; i < 8; ++i) {
#pragma unroll
      for (int r = 0; r < 4; ++r) {
        const int row = r0 + i * 16 + rq + r;
        out[(size_t)row * NSEQ + col] = acc[i][j][r] * scale;
      }
    }
  }
}

extern "C" void kernel_launch(void* const* d_in, const int* in_sizes, int n_in,
                              void* d_out, int out_size, void* d_ws,
                              size_t ws_size, hipStream_t stream) {
  const float* x = (const float*)d_in[0];
  const float* Wq = (const float*)d_in[1];
  const float* bq = (const float*)d_in[2];
  const float* Wk = (const float*)d_in[3];
  const float* bk = (const float*)d_in[4];
  // d_in[5], d_in[6] (W_v, b_v) unused — V never reaches the output.
  float* out = (float*)d_out;

  // workspace layout (64 MB total)
  u16* xb = (u16*)d_ws;                    // 4096x2048 bf16 (16 MB)
  u16* wqb = xb + (size_t)NSEQ * DIMK;     // 2048x2048 bf16 (8 MB)
  u16* wkb = wqb + (size_t)DIMK * DIMK;    // 8 MB
  u16* qb = wkb + (size_t)DIMK * DIMK;     // 16 MB
  u16* kb = qb + (size_t)NSEQ * DIMK;      // 16 MB

  const int totalN4 = (NSEQ * DIMK + 2 * DIMK * DIMK) / 4;
  cast3_f32_bf16<<<totalN4 / 256, 256, 0, stream>>>(x, Wq, Wk, xb, wqb, wkb);

  gemm_qk<<<dim3(DIMK / 256, NSEQ / 256, 2), 512, 0, stream>>>(xb, wqb, wkb,
                                                               bq, bk, qb, kb);

  const float scale = 1.0f / sqrtf((float)DIMK);
  gemm_scores<<<dim3(NSEQ / 256, NSEQ / 256, 1), 512, 0, stream>>>(qb, kb, out,
                                                                   scale);
}

// Round 4
// 262.129 us; speedup vs baseline: 1.2111x; 1.2111x over previous
//
#include <hip/hip_runtime.h>
#include <math.h>

#define DIMK 2048
#define NSEQ 4096
#define NT (DIMK / 64)  // 32 K-tiles of BK=64

typedef short bf16x8 __attribute__((ext_vector_type(8)));
typedef float f32x4 __attribute__((ext_vector_type(4)));
typedef unsigned short u16;
typedef unsigned short u16x8 __attribute__((ext_vector_type(8)));

__device__ __forceinline__ u16 f32_to_bf16(float f) {
  unsigned u = __float_as_uint(f);
  u += 0x7fffu + ((u >> 16) & 1u);  // round-to-nearest-even
  return (u16)(u >> 16);
}

__device__ __forceinline__ void async16(const u16* g, u16* l) {
  __builtin_amdgcn_global_load_lds(
      (const __attribute__((address_space(1))) unsigned int*)g,
      (__attribute__((address_space(3))) unsigned int*)l,
      16, 0, 0);
}

// -------- fused fp32 -> bf16 cast for x, Wq, Wk (one launch, 16B stores) ----
__global__ __launch_bounds__(256) void cast3_f32_bf16(
    const float* __restrict__ x, const float* __restrict__ wq,
    const float* __restrict__ wk, u16* __restrict__ xb,
    u16* __restrict__ wqb, u16* __restrict__ wkb) {
  const int xN8 = NSEQ * DIMK / 8;
  const int wN8 = DIMK * DIMK / 8;
  int i = blockIdx.x * 256 + threadIdx.x;
  const float* src;
  u16* dst;
  int j;
  if (i < xN8) { src = x; dst = xb; j = i; }
  else if (i < xN8 + wN8) { src = wq; dst = wqb; j = i - xN8; }
  else { src = wk; dst = wkb; j = i - xN8 - wN8; }
  float4 v0 = ((const float4*)src)[j * 2];
  float4 v1 = ((const float4*)src)[j * 2 + 1];
  u16x8 o;
  o[0] = f32_to_bf16(v0.x); o[1] = f32_to_bf16(v0.y);
  o[2] = f32_to_bf16(v0.z); o[3] = f32_to_bf16(v0.w);
  o[4] = f32_to_bf16(v1.x); o[5] = f32_to_bf16(v1.y);
  o[6] = f32_to_bf16(v1.z); o[7] = f32_to_bf16(v1.w);
  ((u16x8*)dst)[j] = o;
}

// ===================== 256x256 8-phase NT GEMM mainloop =====================
// Round-1 proven structure (m201 template): per phase {reads; stage; BAR;
// lgkmcnt(0); setprio1; 16 MFMA; setprio0; BAR}, counted vmcnt(6) once per
// K-tile, raw s_barrier only. Parameter deltas vs round-1:
//  - reads distributed 12/4/8/0 (P1: a1+b01 +lgkmcnt(8) pre-barrier;
//    P2: b23; P3: a2; P4: none) instead of 16/0/8/0.
//  - stages: P1: A-bot(t+1)->nxt; P3: B-top+B-bot(t+2)->cur;
//    P4: A-top(t+2)->cur.  (B stage follows b23's P2 retire + barrier.)
//  - MFMA clusters generated by an unrolled-loop macro (kk outer ->
//    k0-sweep over 8 independent accs then k1-sweep). Round-3's failure
//    was a hand-typo in the hand-unrolled cluster table; derived indices
//    eliminate that class.
// Liveness: b01 retires P1-cluster, b23 retires P2-cluster -> B staged P3;
// a1 retires P1... a1 used P1+P2, a2 used P3+P4, both drained by their
// phase LGKM0 + closing barrier before any overwriting stage issues.
// vmcnt(6) at P4 (FIFO) retires A-bot(t), B(t), A-top(t) before tile t's
// first read; the 6 in flight are B(t+1)+A-top(t+1).

#define VM6 asm volatile("s_waitcnt vmcnt(6)" ::: "memory")
#define VM0 asm volatile("s_waitcnt vmcnt(0)" ::: "memory")
#define LGKM8 asm volatile("s_waitcnt lgkmcnt(8)" ::: "memory")
#define LGKM0 asm volatile("s_waitcnt lgkmcnt(0)" ::: "memory")
#define BAR __builtin_amdgcn_s_barrier()
#define PRIO1 __builtin_amdgcn_s_setprio(1)
#define PRIO0 __builtin_amdgcn_s_setprio(0)
#define NOOP ((void)0)

#define ISSUE(g, t_, reg)                                     \
  do {                                                        \
    const u16* _gp = (g) + (size_t)(t_) * 64 + stg_goff;      \
    async16(_gp, (reg) + tid * 8);                            \
    async16(_gp + (size_t)64 * DIMK, (reg) + 4096 + tid * 8); \
  } while (0)

// ---- fragment read helpers ----
#define RD_A1(bi)                                                   \
  _Pragma("unroll") for (int i = 0; i < 4; ++i) {                   \
    a1[i][0] = *(const bf16x8*)&rdA[bi][(i * 16 + fr) * 64 + c0];   \
    a1[i][1] = *(const bf16x8*)&rdA[bi][(i * 16 + fr) * 64 + c1];   \
  }
#define RD_A2(bi)                                                         \
  _Pragma("unroll") for (int i = 0; i < 4; ++i) {                         \
    a2[i][0] = *(const bf16x8*)&rdA[bi][((i + 4) * 16 + fr) * 64 + c0];   \
    a2[i][1] = *(const bf16x8*)&rdA[bi][((i + 4) * 16 + fr) * 64 + c1];   \
  }
#define RD_B01(bi)                                                  \
  _Pragma("unroll") for (int j = 0; j < 2; ++j) {                   \
    b01[j][0] = *(const bf16x8*)&rdB[bi][(j * 16 + fr) * 64 + c0];  \
    b01[j][1] = *(const bf16x8*)&rdB[bi][(j * 16 + fr) * 64 + c1];  \
  }
#define RD_B23(bi)                                                        \
  _Pragma("unroll") for (int j = 0; j < 2; ++j) {                         \
    b23[j][0] = *(const bf16x8*)&rdB[bi][((j + 2) * 16 + fr) * 64 + c0];  \
    b23[j][1] = *(const bf16x8*)&rdB[bi][((j + 2) * 16 + fr) * 64 + c1];  \
  }

// One MFMA cluster: 16 MFMAs = {k0,k1} x {4 A-rows} x {2 B-cols}.
// kk outer => 8 independent accumulators between dependent reuses.
// All indices are compile-time constants after unroll (rule #20 safe).
#define CLUSTER(i0, Aa, Bb, j0)                                          \
  _Pragma("unroll") for (int kk = 0; kk < 2; ++kk)                       \
    _Pragma("unroll") for (int i = 0; i < 4; ++i)                        \
      _Pragma("unroll") for (int j = 0; j < 2; ++j)                      \
        acc[(i0) + i][(j0) + j] =                                        \
            __builtin_amdgcn_mfma_f32_16x16x32_bf16(                     \
                Aa[i][kk], Bb[j][kk], acc[(i0) + i][(j0) + j], 0, 0, 0);

#define CL_P1 CLUSTER(0, a1, b01, 0)
#define CL_P2 CLUSTER(0, a1, b23, 2)
#define CL_P3 CLUSTER(4, a2, b01, 0)
#define CL_P4 CLUSTER(4, a2, b23, 2)

#define TILE(bi, SP1, SP3A, SP3B, SP4, VMW) \
  do {                                      \
    bf16x8 a1[4][2], a2[4][2], b01[2][2], b23[2][2]; \
    /* P1: 12 reads + stage */              \
    RD_A1(bi);                              \
    RD_B01(bi);                             \
    SP1;                                    \
    LGKM8;                                  \
    BAR;                                    \
    LGKM0;                                  \
    PRIO1; CL_P1; PRIO0;                    \
    BAR;                                    \
    /* P2: 4 reads */                       \
    RD_B23(bi);                             \
    BAR;                                    \
    LGKM0;                                  \
    PRIO1; CL_P2; PRIO0;                    \
    BAR;                                    \
    /* P3: 8 reads + 2 stages */            \
    RD_A2(bi);                              \
    SP3A;                                   \
    SP3B;                                   \
    BAR;                                    \
    LGKM0;                                  \
    PRIO1; CL_P3; PRIO0;                    \
    BAR;                                    \
    /* P4: stage + counted vmcnt */         \
    SP4;                                    \
    VMW;                                    \
    BAR;                                    \
    PRIO1; CL_P4; PRIO0;                    \
    BAR;                                    \
  } while (0)

#define TILE_LAST(bi)                       \
  do {                                      \
    bf16x8 a1[4][2], a2[4][2], b01[2][2], b23[2][2]; \
    RD_A1(bi);                              \
    RD_B01(bi);                             \
    BAR;                                    \
    LGKM0;                                  \
    PRIO1; CL_P1; PRIO0;                    \
    BAR;                                    \
    RD_B23(bi);                             \
    BAR;                                    \
    LGKM0;                                  \
    PRIO1; CL_P2; PRIO0;                    \
    BAR;                                    \
    RD_A2(bi);                              \
    BAR;                                    \
    LGKM0;                                  \
    PRIO1; CL_P3; PRIO0;                    \
    BAR;                                    \
    PRIO1; CL_P4; PRIO0;                    \
  } while (0)

__device__ __forceinline__ void mainloop256(
    const u16* __restrict__ A, const u16* __restrict__ B, int rowBase,
    int colBase, u16 (*lds)[2][2][8192], f32x4 acc[8][4]) {
  const int tid = threadIdx.x;
  const int lane = tid & 63;
  const int wid = tid >> 6;
  const int wmg = wid >> 2;  // 0,1 : which 128-row half of A-tile
  const int wng = wid & 3;   // 0..3: which 64-row strip of B-tile
  const int fr = lane & 15;
  const int kq = lane >> 4;

  // staging: thread covers row (tid>>3), phys chunk (tid&7); pre-swizzled
  // global source chunk = (tid&7) ^ (row&7)  (linear LDS dest, swizzled src).
  const int stg_goff =
      (tid >> 3) * DIMK + (((tid & 7) ^ ((tid >> 3) & 7)) * 8);
  // frag-read phys chunk offsets (elements) for k-step 0 / 1
  const int c0 = (kq ^ (fr & 7)) * 8;
  const int c1 = ((4 + kq) ^ (fr & 7)) * 8;

  const u16* gA0 = A + (size_t)rowBase * DIMK;
  const u16* gA1 = gA0 + (size_t)128 * DIMK;
  const u16* gB0 = B + (size_t)colBase * DIMK;
  const u16* gB1 = gB0 + (size_t)128 * DIMK;

  u16* sA0[2] = {&lds[0][0][0][0], &lds[1][0][0][0]};
  u16* sA1[2] = {&lds[0][0][1][0], &lds[1][0][1][0]};
  u16* sB0[2] = {&lds[0][1][0][0], &lds[1][1][0][0]};
  u16* sB1[2] = {&lds[0][1][1][0], &lds[1][1][1][0]};

  const u16* rdA[2] = {&lds[0][0][wmg][0], &lds[1][0][wmg][0]};
  const u16* rdB[2] = {&lds[0][1][wng >> 1][(wng & 1) * 4096],
                       &lds[1][1][wng >> 1][(wng & 1) * 4096]};

  // ---- prologue: tile0 fully + 3/4 of tile1 (A-bot comes at tile0.P1) ----
  ISSUE(gB0, 0, sB0[0]);
  ISSUE(gB1, 0, sB1[0]);
  ISSUE(gA0, 0, sA0[0]);
  ISSUE(gA1, 0, sA1[0]);
  ISSUE(gB0, 1, sB0[1]);
  ISSUE(gB1, 1, sB1[1]);
  ISSUE(gA0, 1, sA0[1]);
  VM6;  // drain tile0's 8 items; tile1's 6 stay in flight
  BAR;

#pragma unroll 1
  for (int t = 0; t < NT - 2; t += 2) {
    TILE(0,
         ISSUE(gA1, t + 1, sA1[1]),   // P1: finish tile t+1 (other buf)
         ISSUE(gB0, t + 2, sB0[0]),   // P3: B-top dead since P2 retire
         ISSUE(gB1, t + 2, sB1[0]),   // P3: B-bot
         ISSUE(gA0, t + 2, sA0[0]),   // P4: A-top dead since P3 retire
         VM6);
    TILE(1,
         ISSUE(gA1, t + 2, sA1[0]),
         ISSUE(gB0, t + 3, sB0[1]),
         ISSUE(gB1, t + 3, sB1[1]),
         ISSUE(gA0, t + 3, sA0[1]),
         VM6);
  }
  // tile NT-2 (buf0): finish staging tile NT-1, full drain, then last tile
  TILE(0, ISSUE(gA1, NT - 1, sA1[1]), NOOP, NOOP, NOOP, VM0);
  TILE_LAST(1);
}

// -------- GEMM1: Q = x Wq^T + bq ; K = x Wk^T + bk  (z selects) --------
__global__ __launch_bounds__(512) void gemm_qk(
    const u16* __restrict__ X, const u16* __restrict__ Wq,
    const u16* __restrict__ Wk, const float* __restrict__ bq,
    const float* __restrict__ bk, u16* __restrict__ Qo, u16* __restrict__ Ko) {
  __shared__ u16 lds[2][2][2][8192];  // 128 KiB
  const u16* Bmat = blockIdx.z ? Wk : Wq;
  const float* bias = blockIdx.z ? bk : bq;
  u16* Out = blockIdx.z ? Ko : Qo;
  const int rowBase = blockIdx.y * 256;
  const int colBase = blockIdx.x * 256;

  f32x4 acc[8][4] = {};
  mainloop256(X, Bmat, rowBase, colBase, lds, acc);

  const int tid = threadIdx.x;
  const int lane = tid & 63;
  const int wid = tid >> 6;
  const int wmg = wid >> 2;
  const int wng = wid & 3;
  const int fr = lane & 15;
  const int rq = (lane >> 4) * 4;
  const int r0 = rowBase + wmg * 128;
  const int cb = colBase + wng * 64;
#pragma unroll
  for (int j = 0; j < 4; ++j) {
    const int col = cb + j * 16 + fr;
    const float bv = bias[col];
#pragma unroll
    for (int i = 0; i < 8; ++i) {
#pragma unroll
      for (int r = 0; r < 4; ++r) {
        const int row = r0 + i * 16 + rq + r;
        Out[(size_t)row * DIMK + col] = f32_to_bf16(acc[i][j][r] + bv);
      }
    }
  }
}

// -------- GEMM2: scores = scale * Q K^T  (bf16 in, fp32 out) --------
__global__ __launch_bounds__(512) void gemm_scores(
    const u16* __restrict__ Qi, const u16* __restrict__ Ki,
    float* __restrict__ out, float scale) {
  __shared__ u16 lds[2][2][2][8192];
  const int rowBase = blockIdx.y * 256;
  const int colBase = blockIdx.x * 256;

  f32x4 acc[8][4] = {};
  mainloop256(Qi, Ki, rowBase, colBase, lds, acc);

  const int tid = threadIdx.x;
  const int lane = tid & 63;
  const int wid = tid >> 6;
  const int wmg = wid >> 2;
  const int wng = wid & 3;
  const int fr = lane & 15;
  const int rq = (lane >> 4) * 4;
  const int r0 = rowBase + wmg * 128;
  const int cb = colBase + wng * 64;
#pragma unroll
  for (int j = 0; j < 4; ++j) {
    const int col = cb + j * 16 + fr;
#pragma unroll
    for (int i = 0; i < 8; ++i) {
#pragma unroll
      for (int r = 0; r < 4; ++r) {
        const int row = r0 + i * 16 + rq + r;
        out[(size_t)row * NSEQ + col] = acc[i][j][r] * scale;
      }
    }
  }
}

extern "C" void kernel_launch(void* const* d_in, const int* in_sizes, int n_in,
                              void* d_out, int out_size, void* d_ws,
                              size_t ws_size, hipStream_t stream) {
  const float* x = (const float*)d_in[0];
  const float* Wq = (const float*)d_in[1];
  const float* bq = (const float*)d_in[2];
  const float* Wk = (const float*)d_in[3];
  const float* bk = (const float*)d_in[4];
  // d_in[5], d_in[6] (W_v, b_v) unused — V never reaches the output.
  float* out = (float*)d_out;

  // workspace layout (64 MB total)
  u16* xb = (u16*)d_ws;                    // 4096x2048 bf16 (16 MB)
  u16* wqb = xb + (size_t)NSEQ * DIMK;     // 2048x2048 bf16 (8 MB)
  u16* wkb = wqb + (size_t)DIMK * DIMK;    // 8 MB
  u16* qb = wkb + (size_t)DIMK * DIMK;     // 16 MB
  u16* kb = qb + (size_t)NSEQ * DIMK;      // 16 MB

  const int total8 = (NSEQ * DIMK + 2 * DIMK * DIMK) / 8;
  cast3_f32_bf16<<<total8 / 256, 256, 0, stream>>>(x, Wq, Wk, xb, wqb, wkb);

  gemm_qk<<<dim3(DIMK / 256, NSEQ / 256, 2), 512, 0, stream>>>(xb, wqb, wkb,
                                                               bq, bk, qb, kb);

  const float scale = 1.0f / sqrtf((float)DIMK);
  gemm_scores<<<dim3(NSEQ / 256, NSEQ / 256, 1), 512, 0, stream>>>(qb, kb, out,
                                                                   scale);
}

// Round 5
// 254.889 us; speedup vs baseline: 1.2455x; 1.0284x over previous
//
#include <hip/hip_runtime.h>
#include <math.h>

#define DIMK 2048
#define NSEQ 4096
#define NT (DIMK / 64)  // 32 K-tiles of BK=64
#define EPS 264          // epilogue LDS row stride (u16) — bank-spread

typedef short bf16x8 __attribute__((ext_vector_type(8)));
typedef float f32x4 __attribute__((ext_vector_type(4)));
typedef unsigned short u16;
typedef unsigned short u16x8 __attribute__((ext_vector_type(8)));

__device__ __forceinline__ u16 f32_to_bf16(float f) {
  unsigned u = __float_as_uint(f);
  u += 0x7fffu + ((u >> 16) & 1u);  // round-to-nearest-even
  return (u16)(u >> 16);
}

__device__ __forceinline__ void async16(const u16* g, u16* l) {
  __builtin_amdgcn_global_load_lds(
      (const __attribute__((address_space(1))) unsigned int*)g,
      (__attribute__((address_space(3))) unsigned int*)l,
      16, 0, 0);
}

// -------- fused fp32 -> bf16 cast for x, Wq, Wk (one launch, 16B stores) ----
__global__ __launch_bounds__(256) void cast3_f32_bf16(
    const float* __restrict__ x, const float* __restrict__ wq,
    const float* __restrict__ wk, u16* __restrict__ xb,
    u16* __restrict__ wqb, u16* __restrict__ wkb) {
  const int xN8 = NSEQ * DIMK / 8;
  const int wN8 = DIMK * DIMK / 8;
  int i = blockIdx.x * 256 + threadIdx.x;
  const float* src;
  u16* dst;
  int j;
  if (i < xN8) { src = x; dst = xb; j = i; }
  else if (i < xN8 + wN8) { src = wq; dst = wqb; j = i - xN8; }
  else { src = wk; dst = wkb; j = i - xN8 - wN8; }
  float4 v0 = ((const float4*)src)[j * 2];
  float4 v1 = ((const float4*)src)[j * 2 + 1];
  u16x8 o;
  o[0] = f32_to_bf16(v0.x); o[1] = f32_to_bf16(v0.y);
  o[2] = f32_to_bf16(v0.z); o[3] = f32_to_bf16(v0.w);
  o[4] = f32_to_bf16(v1.x); o[5] = f32_to_bf16(v1.y);
  o[6] = f32_to_bf16(v1.z); o[7] = f32_to_bf16(v1.w);
  ((u16x8*)dst)[j] = o;
}

// ===================== 256x256 8-phase NT GEMM mainloop =====================
// Round-4 verified structure (m201 template) — UNCHANGED this round.
// Per phase {reads; stage; BAR; lgkmcnt(0); setprio1; 16 MFMA; setprio0;
// BAR}, counted vmcnt(6) once per K-tile, raw s_barrier only.
// Liveness: b01 retires P1, b23 retires P2 -> B staged P3; a1 used P1+P2,
// a2 used P3+P4, drained by phase LGKM0 + closing barrier before any
// overwriting stage. vmcnt(6) at P4 (FIFO) retires A-bot(t+1)'s pair;
// the 6 in flight are B(t+2)[4] + A-top(t+2)[2].

#define VM6 asm volatile("s_waitcnt vmcnt(6)" ::: "memory")
#define VM0 asm volatile("s_waitcnt vmcnt(0)" ::: "memory")
#define LGKM8 asm volatile("s_waitcnt lgkmcnt(8)" ::: "memory")
#define LGKM0 asm volatile("s_waitcnt lgkmcnt(0)" ::: "memory")
#define BAR __builtin_amdgcn_s_barrier()
#define PRIO1 __builtin_amdgcn_s_setprio(1)
#define PRIO0 __builtin_amdgcn_s_setprio(0)
#define NOOP ((void)0)

#define ISSUE(g, t_, reg)                                     \
  do {                                                        \
    const u16* _gp = (g) + (size_t)(t_) * 64 + stg_goff;      \
    async16(_gp, (reg) + tid * 8);                            \
    async16(_gp + (size_t)64 * DIMK, (reg) + 4096 + tid * 8); \
  } while (0)

// ---- fragment read helpers ----
#define RD_A1(bi)                                                   \
  _Pragma("unroll") for (int i = 0; i < 4; ++i) {                   \
    a1[i][0] = *(const bf16x8*)&rdA[bi][(i * 16 + fr) * 64 + c0];   \
    a1[i][1] = *(const bf16x8*)&rdA[bi][(i * 16 + fr) * 64 + c1];   \
  }
#define RD_A2(bi)                                                         \
  _Pragma("unroll") for (int i = 0; i < 4; ++i) {                         \
    a2[i][0] = *(const bf16x8*)&rdA[bi][((i + 4) * 16 + fr) * 64 + c0];   \
    a2[i][1] = *(const bf16x8*)&rdA[bi][((i + 4) * 16 + fr) * 64 + c1];   \
  }
#define RD_B01(bi)                                                  \
  _Pragma("unroll") for (int j = 0; j < 2; ++j) {                   \
    b01[j][0] = *(const bf16x8*)&rdB[bi][(j * 16 + fr) * 64 + c0];  \
    b01[j][1] = *(const bf16x8*)&rdB[bi][(j * 16 + fr) * 64 + c1];  \
  }
#define RD_B23(bi)                                                        \
  _Pragma("unroll") for (int j = 0; j < 2; ++j) {                         \
    b23[j][0] = *(const bf16x8*)&rdB[bi][((j + 2) * 16 + fr) * 64 + c0];  \
    b23[j][1] = *(const bf16x8*)&rdB[bi][((j + 2) * 16 + fr) * 64 + c1];  \
  }

// One MFMA cluster: 16 MFMAs = {k0,k1} x {4 A-rows} x {2 B-cols}.
// kk outer => 8 independent accumulators between dependent reuses.
// All indices compile-time constants after unroll (rule #20 safe).
#define CLUSTER(i0, Aa, Bb, j0)                                          \
  _Pragma("unroll") for (int kk = 0; kk < 2; ++kk)                       \
    _Pragma("unroll") for (int i = 0; i < 4; ++i)                        \
      _Pragma("unroll") for (int j = 0; j < 2; ++j)                      \
        acc[(i0) + i][(j0) + j] =                                        \
            __builtin_amdgcn_mfma_f32_16x16x32_bf16(                     \
                Aa[i][kk], Bb[j][kk], acc[(i0) + i][(j0) + j], 0, 0, 0);

#define CL_P1 CLUSTER(0, a1, b01, 0)
#define CL_P2 CLUSTER(0, a1, b23, 2)
#define CL_P3 CLUSTER(4, a2, b01, 0)
#define CL_P4 CLUSTER(4, a2, b23, 2)

#define TILE(bi, SP1, SP3A, SP3B, SP4, VMW) \
  do {                                      \
    bf16x8 a1[4][2], a2[4][2], b01[2][2], b23[2][2]; \
    /* P1: 12 reads + stage */              \
    RD_A1(bi);                              \
    RD_B01(bi);                             \
    SP1;                                    \
    LGKM8;                                  \
    BAR;                                    \
    LGKM0;                                  \
    PRIO1; CL_P1; PRIO0;                    \
    BAR;                                    \
    /* P2: 4 reads */                       \
    RD_B23(bi);                             \
    BAR;                                    \
    LGKM0;                                  \
    PRIO1; CL_P2; PRIO0;                    \
    BAR;                                    \
    /* P3: 8 reads + 2 stages */            \
    RD_A2(bi);                              \
    SP3A;                                   \
    SP3B;                                   \
    BAR;                                    \
    LGKM0;                                  \
    PRIO1; CL_P3; PRIO0;                    \
    BAR;                                    \
    /* P4: stage + counted vmcnt */         \
    SP4;                                    \
    VMW;                                    \
    BAR;                                    \
    PRIO1; CL_P4; PRIO0;                    \
    BAR;                                    \
  } while (0)

#define TILE_LAST(bi)                       \
  do {                                      \
    bf16x8 a1[4][2], a2[4][2], b01[2][2], b23[2][2]; \
    RD_A1(bi);                              \
    RD_B01(bi);                             \
    BAR;                                    \
    LGKM0;                                  \
    PRIO1; CL_P1; PRIO0;                    \
    BAR;                                    \
    RD_B23(bi);                             \
    BAR;                                    \
    LGKM0;                                  \
    PRIO1; CL_P2; PRIO0;                    \
    BAR;                                    \
    RD_A2(bi);                              \
    BAR;                                    \
    LGKM0;                                  \
    PRIO1; CL_P3; PRIO0;                    \
    BAR;                                    \
    PRIO1; CL_P4; PRIO0;                    \
  } while (0)

__device__ __forceinline__ void mainloop256(
    const u16* __restrict__ A, const u16* __restrict__ B, int rowBase,
    int colBase, u16 (*lds)[2][2][8192], f32x4 acc[8][4]) {
  const int tid = threadIdx.x;
  const int lane = tid & 63;
  const int wid = tid >> 6;
  const int wmg = wid >> 2;  // 0,1 : which 128-row half of A-tile
  const int wng = wid & 3;   // 0..3: which 64-row strip of B-tile
  const int fr = lane & 15;
  const int kq = lane >> 4;

  // staging: thread covers row (tid>>3), phys chunk (tid&7); pre-swizzled
  // global source chunk = (tid&7) ^ (row&7)  (linear LDS dest, swizzled src).
  const int stg_goff =
      (tid >> 3) * DIMK + (((tid & 7) ^ ((tid >> 3) & 7)) * 8);
  // frag-read phys chunk offsets (elements) for k-step 0 / 1
  const int c0 = (kq ^ (fr & 7)) * 8;
  const int c1 = ((4 + kq) ^ (fr & 7)) * 8;

  const u16* gA0 = A + (size_t)rowBase * DIMK;
  const u16* gA1 = gA0 + (size_t)128 * DIMK;
  const u16* gB0 = B + (size_t)colBase * DIMK;
  const u16* gB1 = gB0 + (size_t)128 * DIMK;

  u16* sA0[2] = {&lds[0][0][0][0], &lds[1][0][0][0]};
  u16* sA1[2] = {&lds[0][0][1][0], &lds[1][0][1][0]};
  u16* sB0[2] = {&lds[0][1][0][0], &lds[1][1][0][0]};
  u16* sB1[2] = {&lds[0][1][1][0], &lds[1][1][1][0]};

  const u16* rdA[2] = {&lds[0][0][wmg][0], &lds[1][0][wmg][0]};
  const u16* rdB[2] = {&lds[0][1][wng >> 1][(wng & 1) * 4096],
                       &lds[1][1][wng >> 1][(wng & 1) * 4096]};

  // ---- prologue: tile0 fully + 3/4 of tile1 (A-bot comes at tile0.P1) ----
  ISSUE(gB0, 0, sB0[0]);
  ISSUE(gB1, 0, sB1[0]);
  ISSUE(gA0, 0, sA0[0]);
  ISSUE(gA1, 0, sA1[0]);
  ISSUE(gB0, 1, sB0[1]);
  ISSUE(gB1, 1, sB1[1]);
  ISSUE(gA0, 1, sA0[1]);
  VM6;  // drain tile0's 8 items; tile1's 6 stay in flight
  BAR;

#pragma unroll 1
  for (int t = 0; t < NT - 2; t += 2) {
    TILE(0,
         ISSUE(gA1, t + 1, sA1[1]),   // P1: finish tile t+1 (other buf)
         ISSUE(gB0, t + 2, sB0[0]),   // P3: B-top dead since P2 retire
         ISSUE(gB1, t + 2, sB1[0]),   // P3: B-bot
         ISSUE(gA0, t + 2, sA0[0]),   // P4: A-top dead since P3 retire
         VM6);
    TILE(1,
         ISSUE(gA1, t + 2, sA1[0]),
         ISSUE(gB0, t + 3, sB0[1]),
         ISSUE(gB1, t + 3, sB1[1]),
         ISSUE(gA0, t + 3, sA0[1]),
         VM6);
  }
  // tile NT-2 (buf0): finish staging tile NT-1, full drain, then last tile
  TILE(0, ISSUE(gA1, NT - 1, sA1[1]), NOOP, NOOP, NOOP, VM0);
  TILE_LAST(1);
}

// -------- GEMM1: Q = x Wq^T + bq ; K = x Wk^T + bk  (z selects) --------
// Epilogue: LDS-bounce transpose -> fully coalesced 16B bf16 stores.
// (Old scattered 2B stores caused 2.4x HBM write-amp + RMW fetch: 64B
// lines written as two 32B halves, evicted from L2 between halves.)
__global__ __launch_bounds__(512) void gemm_qk(
    const u16* __restrict__ X, const u16* __restrict__ Wq,
    const u16* __restrict__ Wk, const float* __restrict__ bq,
    const float* __restrict__ bk, u16* __restrict__ Qo, u16* __restrict__ Ko) {
  __shared__ u16 sraw[256 * EPS];  // 132 KiB: mainloop overlay + epilogue tile
  const u16* Bmat = blockIdx.z ? Wk : Wq;
  const float* bias = blockIdx.z ? bk : bq;
  u16* Out = blockIdx.z ? Ko : Qo;
  const int rowBase = blockIdx.y * 256;
  const int colBase = blockIdx.x * 256;

  f32x4 acc[8][4] = {};
  mainloop256(X, Bmat, rowBase, colBase, (u16(*)[2][2][8192])sraw, acc);

  const int tid = threadIdx.x;
  const int lane = tid & 63;
  const int wid = tid >> 6;
  const int wmg = wid >> 2;
  const int wng = wid & 3;
  const int fr = lane & 15;
  const int rq = (lane >> 4) * 4;

  __syncthreads();  // all waves done with mainloop LDS before overwrite
#pragma unroll
  for (int j = 0; j < 4; ++j) {
    const int col = wng * 64 + j * 16 + fr;
    const float bv = bias[colBase + col];
#pragma unroll
    for (int i = 0; i < 8; ++i) {
#pragma unroll
      for (int r = 0; r < 4; ++r) {
        const int row = wmg * 128 + i * 16 + rq + r;
        sraw[row * EPS + col] = f32_to_bf16(acc[i][j][r] + bv);
      }
    }
  }
  __syncthreads();  // LDS tile complete (lgkm drained by syncthreads)
  const int rl = tid >> 5;   // 0..15
  const int c16 = tid & 31;  // which 16B chunk of the row
#pragma unroll
  for (int p = 0; p < 16; ++p) {
    const int row = p * 16 + rl;
    u16x8 v = *(const u16x8*)&sraw[row * EPS + c16 * 8];
    *(u16x8*)&Out[(size_t)(rowBase + row) * DIMK + colBase + c16 * 8] = v;
  }
}

// -------- GEMM2: scores = scale * Q K^T  (bf16 in, fp32 out) --------
// f32 stores are already full-64B-line per wave-instruction: keep direct.
__global__ __launch_bounds__(512) void gemm_scores(
    const u16* __restrict__ Qi, const u16* __restrict__ Ki,
    float* __restrict__ out, float scale) {
  __shared__ u16 lds[2][2][2][8192];
  const int rowBase = blockIdx.y * 256;
  const int colBase = blockIdx.x * 256;

  f32x4 acc[8][4] = {};
  mainloop256(Qi, Ki, rowBase, colBase, lds, acc);

  const int tid = threadIdx.x;
  const int lane = tid & 63;
  const int wid = tid >> 6;
  const int wmg = wid >> 2;
  const int wng = wid & 3;
  const int fr = lane & 15;
  const int rq = (lane >> 4) * 4;
  const int r0 = rowBase + wmg * 128;
  const int cb = colBase + wng * 64;
#pragma unroll
  for (int j = 0; j < 4; ++j) {
    const int col = cb + j * 16 + fr;
#pragma unroll
    for (int i = 0; i < 8; ++i) {
#pragma unroll
      for (int r = 0; r < 4; ++r) {
        const int row = r0 + i * 16 + rq + r;
        out[(size_t)row * NSEQ + col] = acc[i][j][r] * scale;
      }
    }
  }
}

extern "C" void kernel_launch(void* const* d_in, const int* in_sizes, int n_in,
                              void* d_out, int out_size, void* d_ws,
                              size_t ws_size, hipStream_t stream) {
  const float* x = (const float*)d_in[0];
  const float* Wq = (const float*)d_in[1];
  const float* bq = (const float*)d_in[2];
  const float* Wk = (const float*)d_in[3];
  const float* bk = (const float*)d_in[4];
  // d_in[5], d_in[6] (W_v, b_v) unused — V never reaches the output.
  float* out = (float*)d_out;

  // workspace layout (64 MB total)
  u16* xb = (u16*)d_ws;                    // 4096x2048 bf16 (16 MB)
  u16* wqb = xb + (size_t)NSEQ * DIMK;     // 2048x2048 bf16 (8 MB)
  u16* wkb = wqb + (size_t)DIMK * DIMK;    // 8 MB
  u16* qb = wkb + (size_t)DIMK * DIMK;     // 16 MB
  u16* kb = qb + (size_t)NSEQ * DIMK;      // 16 MB

  const int total8 = (NSEQ * DIMK + 2 * DIMK * DIMK) / 8;
  cast3_f32_bf16<<<total8 / 256, 256, 0, stream>>>(x, Wq, Wk, xb, wqb, wkb);

  gemm_qk<<<dim3(DIMK / 256, NSEQ / 256, 2), 512, 0, stream>>>(xb, wqb, wkb,
                                                               bq, bk, qb, kb);

  const float scale = 1.0f / sqrtf((float)DIMK);
  gemm_scores<<<dim3(NSEQ / 256, NSEQ / 256, 1), 512, 0, stream>>>(qb, kb, out,
                                                                   scale);
}

// Round 7
// 251.277 us; speedup vs baseline: 1.2634x; 1.0144x over previous
//
#include <hip/hip_runtime.h>
#include <math.h>

#define DIMK 2048
#define NSEQ 4096
#define NT (DIMK / 64)  // 32 K-tiles of BK=64
#define EPS 264          // epilogue LDS row stride (u16) — bank-spread

typedef short bf16x8 __attribute__((ext_vector_type(8)));
typedef float f32x4 __attribute__((ext_vector_type(4)));
typedef unsigned short u16;
typedef unsigned short u16x8 __attribute__((ext_vector_type(8)));

__device__ __forceinline__ u16 f32_to_bf16(float f) {
  unsigned u = __float_as_uint(f);
  u += 0x7fffu + ((u >> 16) & 1u);  // round-to-nearest-even
  return (u16)(u >> 16);
}

__device__ __forceinline__ void async16(const u16* g, u16* l) {
  __builtin_amdgcn_global_load_lds(
      (const __attribute__((address_space(1))) unsigned int*)g,
      (__attribute__((address_space(3))) unsigned int*)l,
      16, 0, 0);
}

// -------- fused fp32 -> bf16 cast for x, Wq, Wk (one launch, 16B stores) ----
__global__ __launch_bounds__(256) void cast3_f32_bf16(
    const float* __restrict__ x, const float* __restrict__ wq,
    const float* __restrict__ wk, u16* __restrict__ xb,
    u16* __restrict__ wqb, u16* __restrict__ wkb) {
  const int xN8 = NSEQ * DIMK / 8;
  const int wN8 = DIMK * DIMK / 8;
  int i = blockIdx.x * 256 + threadIdx.x;
  const float* src;
  u16* dst;
  int j;
  if (i < xN8) { src = x; dst = xb; j = i; }
  else if (i < xN8 + wN8) { src = wq; dst = wqb; j = i - xN8; }
  else { src = wk; dst = wkb; j = i - xN8 - wN8; }
  float4 v0 = ((const float4*)src)[j * 2];
  float4 v1 = ((const float4*)src)[j * 2 + 1];
  u16x8 o;
  o[0] = f32_to_bf16(v0.x); o[1] = f32_to_bf16(v0.y);
  o[2] = f32_to_bf16(v0.z); o[3] = f32_to_bf16(v0.w);
  o[4] = f32_to_bf16(v1.x); o[5] = f32_to_bf16(v1.y);
  o[6] = f32_to_bf16(v1.z); o[7] = f32_to_bf16(v1.w);
  ((u16x8*)dst)[j] = o;
}

// ============ 256x256 woven 4-phase NT GEMM mainloop (round 6) ============
// 8 waves (2M x 4N), per-wave 128x64 out, BK=64 double-buffered.
// KEY CHANGE vs round-4 (37% MfmaUtil ceiling): ds_reads are WOVEN INTO the
// MFMA clusters one phase ahead of their consuming cluster, with NO explicit
// lgkm waits — the compiler's fine-grained counted lgkmcnt overlaps read
// completion with MFMA issue instead of the old {reads; BAR; lgkm0; MFMA}
// full-drain serialization (reads ~1500 cyc/K-tile were serialized against
// ~2060 cyc of MFMA). One barrier per phase (4/K-tile):
//   P1: {HALF_kk0(a1xb01) | rd b23(cur) | HALF_kk1} BAR
//   P2: stage A-bot(t+1)->nxt; {HALF_kk0(a1xb23) | rd a2(cur) | HALF_kk1} BAR
//   P3: {HALF_kk0(a2xb01)  HALF_kk1} BAR
//   P4: stage B(t+2)->cur, A-top(t+2)->cur; vmcnt(6);
//       {HALF_kk0(a2xb23) | rd a1',b01'(nxt) | HALF_kk1} BAR
// Safety ledger (consumption-guarantee + barrier transitivity):
//  - a read is COMPLETE before its wave's first dependent MFMA issues
//    (compiler lgkm), hence before that wave's next barrier.
//  - every stage issues at a phase START, i.e. >=1 barrier after ALL waves'
//    consumption of the region it overwrites:
//      b23(cur) consumed in P2 < BAR(P2) <= BAR(P3) < B-stage (P4-start)
//      a2(cur)  consumed in P3 < BAR(P3) < A-top stage (P4-start)
//      a1'/b01'(nxt) consumed next-P1 < BAR(P1') << next stages
//      A-bot(nxt) region: prev-tile P4 reads consumed in P1 < BAR(P1) < SP1
//  - vmcnt FIFO at P4: in-flight = carried 6 [B(t+1),Atop(t+1)] +
//    Abot(t+1)[P2] + B(t+2)[4] + Atop(t+2)[2] = 14; vmcnt(6) retires 8 =
//    ALL of tile t+1 before the a1'/b01' reads (pinned after the vmcnt by
//    its "memory" clobber). Leaves exactly B(t+2)+Atop(t+2)=6 carried.

#define VM6 asm volatile("s_waitcnt vmcnt(6)" ::: "memory")
#define VM0 asm volatile("s_waitcnt vmcnt(0)" ::: "memory")
#define BAR __builtin_amdgcn_s_barrier()
#define PRIO1 __builtin_amdgcn_s_setprio(1)
#define PRIO0 __builtin_amdgcn_s_setprio(0)
#define NOOP ((void)0)

#define ISSUE(g, t_, reg)                                     \
  do {                                                        \
    const u16* _gp = (g) + (size_t)(t_) * 64 + stg_goff;      \
    async16(_gp, (reg) + tid * 8);                            \
    async16(_gp + (size_t)64 * DIMK, (reg) + 4096 + tid * 8); \
  } while (0)

// ---- fragment read helpers (fragments live at mainloop scope) ----
#define RD_A1(bi)                                                   \
  _Pragma("unroll") for (int i = 0; i < 4; ++i) {                   \
    a1[i][0] = *(const bf16x8*)&rdA[bi][(i * 16 + fr) * 64 + c0];   \
    a1[i][1] = *(const bf16x8*)&rdA[bi][(i * 16 + fr) * 64 + c1];   \
  }
#define RD_A2(bi)                                                         \
  _Pragma("unroll") for (int i = 0; i < 4; ++i) {                         \
    a2[i][0] = *(const bf16x8*)&rdA[bi][((i + 4) * 16 + fr) * 64 + c0];   \
    a2[i][1] = *(const bf16x8*)&rdA[bi][((i + 4) * 16 + fr) * 64 + c1];   \
  }
#define RD_B01(bi)                                                  \
  _Pragma("unroll") for (int j = 0; j < 2; ++j) {                   \
    b01[j][0] = *(const bf16x8*)&rdB[bi][(j * 16 + fr) * 64 + c0];  \
    b01[j][1] = *(const bf16x8*)&rdB[bi][(j * 16 + fr) * 64 + c1];  \
  }
#define RD_B23(bi)                                                        \
  _Pragma("unroll") for (int j = 0; j < 2; ++j) {                         \
    b23[j][0] = *(const bf16x8*)&rdB[bi][((j + 2) * 16 + fr) * 64 + c0];  \
    b23[j][1] = *(const bf16x8*)&rdB[bi][((j + 2) * 16 + fr) * 64 + c1];  \
  }

// Half-cluster: 8 independent MFMAs (one kk sweep of a C-quadrant).
#define HALF(kk, i0, Aa, j0, Bb)                                         \
  _Pragma("unroll") for (int i = 0; i < 4; ++i)                          \
    _Pragma("unroll") for (int j = 0; j < 2; ++j)                        \
      acc[(i0) + i][(j0) + j] =                                          \
          __builtin_amdgcn_mfma_f32_16x16x32_bf16(                       \
              Aa[i][kk], Bb[j][kk], acc[(i0) + i][(j0) + j], 0, 0, 0);

#define TILE(bi, SP1, SP3A, SP3B, SP4, VMW)  \
  do {                                       \
    /* P1: a1 x b01, weave b23 reads */      \
    PRIO1;                                   \
    HALF(0, 0, a1, 0, b01)                   \
    RD_B23(bi);                              \
    HALF(1, 0, a1, 0, b01)                   \
    PRIO0;                                   \
    BAR;                                     \
    /* P2: a1 x b23, weave a2 reads */       \
    SP1;                                     \
    PRIO1;                                   \
    HALF(0, 0, a1, 2, b23)                   \
    RD_A2(bi);                               \
    HALF(1, 0, a1, 2, b23)                   \
    PRIO0;                                   \
    BAR;                                     \
    /* P3: a2 x b01 */                       \
    PRIO1;                                   \
    HALF(0, 4, a2, 0, b01)                   \
    HALF(1, 4, a2, 0, b01)                   \
    PRIO0;                                   \
    BAR;                                     \
    /* P4: stages + counted vmcnt, a2 x b23, weave next-buf a1/b01 reads */ \
    SP3A;                                    \
    SP3B;                                    \
    SP4;                                     \
    VMW;                                     \
    PRIO1;                                   \
    HALF(0, 4, a2, 2, b23)                   \
    RD_A1((bi) ^ 1);                         \
    RD_B01((bi) ^ 1);                        \
    HALF(1, 4, a2, 2, b23)                   \
    PRIO0;                                   \
    BAR;                                     \
  } while (0)

// Last K-tile: pure dataflow, no stages, no barriers needed.
#define TILE_LAST(bi)           \
  do {                          \
    PRIO1;                      \
    HALF(0, 0, a1, 0, b01)      \
    RD_B23(bi);                 \
    HALF(1, 0, a1, 0, b01)      \
    HALF(0, 0, a1, 2, b23)      \
    RD_A2(bi);                  \
    HALF(1, 0, a1, 2, b23)      \
    HALF(0, 4, a2, 0, b01)      \
    HALF(1, 4, a2, 0, b01)      \
    HALF(0, 4, a2, 2, b23)      \
    HALF(1, 4, a2, 2, b23)      \
    PRIO0;                      \
  } while (0)

__device__ __forceinline__ void mainloop256(
    const u16* __restrict__ A, const u16* __restrict__ B, int rowBase,
    int colBase, u16 (*lds)[2][2][8192], f32x4 acc[8][4]) {
  const int tid = threadIdx.x;
  const int lane = tid & 63;
  const int wid = tid >> 6;
  const int wmg = wid >> 2;  // 0,1 : which 128-row half of A-tile
  const int wng = wid & 3;   // 0..3: which 64-row strip of B-tile
  const int fr = lane & 15;
  const int kq = lane >> 4;

  // staging: thread covers row (tid>>3), phys chunk (tid&7); pre-swizzled
  // global source chunk = (tid&7) ^ (row&7)  (linear LDS dest, swizzled src).
  const int stg_goff =
      (tid >> 3) * DIMK + (((tid & 7) ^ ((tid >> 3) & 7)) * 8);
  // frag-read phys chunk offsets (elements) for k-step 0 / 1
  const int c0 = (kq ^ (fr & 7)) * 8;
  const int c1 = ((4 + kq) ^ (fr & 7)) * 8;

  const u16* gA0 = A + (size_t)rowBase * DIMK;
  const u16* gA1 = gA0 + (size_t)128 * DIMK;
  const u16* gB0 = B + (size_t)colBase * DIMK;
  const u16* gB1 = gB0 + (size_t)128 * DIMK;

  u16* sA0[2] = {&lds[0][0][0][0], &lds[1][0][0][0]};
  u16* sA1[2] = {&lds[0][0][1][0], &lds[1][0][1][0]};
  u16* sB0[2] = {&lds[0][1][0][0], &lds[1][1][0][0]};
  u16* sB1[2] = {&lds[0][1][1][0], &lds[1][1][1][0]};

  const u16* rdA[2] = {&lds[0][0][wmg][0], &lds[1][0][wmg][0]};
  const u16* rdB[2] = {&lds[0][1][wng >> 1][(wng & 1) * 4096],
                       &lds[1][1][wng >> 1][(wng & 1) * 4096]};

  // fragments live across phases/tiles (read-ahead passes them forward)
  bf16x8 a1[4][2], a2[4][2], b01[2][2], b23[2][2];

  // ---- prologue: tile0 fully (8 ops) + B(1)+A-top(1) (6 ops) ----
  ISSUE(gB0, 0, sB0[0]);
  ISSUE(gB1, 0, sB1[0]);
  ISSUE(gA0, 0, sA0[0]);
  ISSUE(gA1, 0, sA1[0]);
  ISSUE(gB0, 1, sB0[1]);
  ISSUE(gB1, 1, sB1[1]);
  ISSUE(gA0, 1, sA0[1]);
  VM6;  // retire tile0's 8; leave B(1)+A-top(1)=6 in flight (steady carry)
  BAR;
  RD_A1(0);   // pinned below VM6 by its clobber; consumed by first CL_P1
  RD_B01(0);

#pragma unroll 1
  for (int t = 0; t < NT - 2; t += 2) {
    TILE(0,
         ISSUE(gA1, t + 1, sA1[1]),   // P2-start: A-bot(t+1) -> buf1
         ISSUE(gB0, t + 2, sB0[0]),   // P4-start: B(t+2) -> buf0
         ISSUE(gB1, t + 2, sB1[0]),
         ISSUE(gA0, t + 2, sA0[0]),   // P4-start: A-top(t+2) -> buf0
         VM6);
    TILE(1,
         ISSUE(gA1, t + 2, sA1[0]),
         ISSUE(gB0, t + 3, sB0[1]),
         ISSUE(gB1, t + 3, sB1[1]),
         ISSUE(gA0, t + 3, sA0[1]),
         VM6);
  }
  // tile NT-2 (buf0): stage A-bot(NT-1), full drain at P4, then last tile
  TILE(0, ISSUE(gA1, NT - 1, sA1[1]), NOOP, NOOP, NOOP, VM0);
  TILE_LAST(1);
}

// -------- GEMM1: Q = x Wq^T + bq ; K = x Wk^T + bk  (z selects) --------
// Epilogue: LDS-bounce transpose -> fully coalesced 16B bf16 stores
// (round-5 verified: removes the 2.4x HBM write-amp of scattered 2B stores).
__global__ __launch_bounds__(512, 2) void gemm_qk(
    const u16* __restrict__ X, const u16* __restrict__ Wq,
    const u16* __restrict__ Wk, const float* __restrict__ bq,
    const float* __restrict__ bk, u16* __restrict__ Qo, u16* __restrict__ Ko) {
  __shared__ u16 sraw[256 * EPS];  // 132 KiB: mainloop overlay + epilogue tile
  const u16* Bmat = blockIdx.z ? Wk : Wq;
  const float* bias = blockIdx.z ? bk : bq;
  u16* Out = blockIdx.z ? Ko : Qo;
  const int rowBase = blockIdx.y * 256;
  const int colBase = blockIdx.x * 256;

  f32x4 acc[8][4] = {};
  mainloop256(X, Bmat, rowBase, colBase, (u16(*)[2][2][8192])sraw, acc);

  const int tid = threadIdx.x;
  const int lane = tid & 63;
  const int wid = tid >> 6;
  const int wmg = wid >> 2;
  const int wng = wid & 3;
  const int fr = lane & 15;
  const int rq = (lane >> 4) * 4;

  __syncthreads();  // all waves done with mainloop LDS before overwrite
#pragma unroll
  for (int j = 0; j < 4; ++j) {
    const int col = wng * 64 + j * 16 + fr;
    const float bv = bias[colBase + col];
#pragma unroll
    for (int i = 0; i < 8; ++i) {
#pragma unroll
      for (int r = 0; r < 4; ++r) {
        const int row = wmg * 128 + i * 16 + rq + r;
        sraw[row * EPS + col] = f32_to_bf16(acc[i][j][r] + bv);
      }
    }
  }
  __syncthreads();  // LDS tile complete
  const int rl = tid >> 5;   // 0..15
  const int c16 = tid & 31;  // which 16B chunk of the row
#pragma unroll
  for (int p = 0; p < 16; ++p) {
    const int row = p * 16 + rl;
    u16x8 v = *(const u16x8*)&sraw[row * EPS + c16 * 8];
    *(u16x8*)&Out[(size_t)(rowBase + row) * DIMK + colBase + c16 * 8] = v;
  }
}

// -------- GEMM2: scores = scale * Q K^T  (bf16 in, fp32 out) --------
// f32 stores are already full-64B-line per wave-instruction: keep direct.
__global__ __launch_bounds__(512, 2) void gemm_scores(
    const u16* __restrict__ Qi, const u16* __restrict__ Ki,
    float* __restrict__ out, float scale) {
  __shared__ u16 lds[2][2][2][8192];
  const int rowBase = blockIdx.y * 256;
  const int colBase = blockIdx.x * 256;

  f32x4 acc[8][4] = {};
  mainloop256(Qi, Ki, rowBase, colBase, lds, acc);

  const int tid = threadIdx.x;
  const int lane = tid & 63;
  const int wid = tid >> 6;
  const int wmg = wid >> 2;
  const int wng = wid & 3;
  const int fr = lane & 15;
  const int rq = (lane >> 4) * 4;
  const int r0 = rowBase + wmg * 128;
  const int cb = colBase + wng * 64;
#pragma unroll
  for (int j = 0; j < 4; ++j) {
    const int col = cb + j * 16 + fr;
#pragma unroll
    for (int i = 0; i < 8; ++i) {
#pragma unroll
      for (int r = 0; r < 4; ++r) {
        const int row = r0 + i * 16 + rq + r;
        out[(size_t)row * NSEQ + col] = acc[i][j][r] * scale;
      }
    }
  }
}

extern "C" void kernel_launch(void* const* d_in, const int* in_sizes, int n_in,
                              void* d_out, int out_size, void* d_ws,
                              size_t ws_size, hipStream_t stream) {
  const float* x = (const float*)d_in[0];
  const float* Wq = (const float*)d_in[1];
  const float* bq = (const float*)d_in[2];
  const float* Wk = (const float*)d_in[3];
  const float* bk = (const float*)d_in[4];
  // d_in[5], d_in[6] (W_v, b_v) unused — V never reaches the output.
  float* out = (float*)d_out;

  // workspace layout (64 MB total)
  u16* xb = (u16*)d_ws;                    // 4096x2048 bf16 (16 MB)
  u16* wqb = xb + (size_t)NSEQ * DIMK;     // 2048x2048 bf16 (8 MB)
  u16* wkb = wqb + (size_t)DIMK * DIMK;    // 8 MB
  u16* qb = wkb + (size_t)DIMK * DIMK;     // 16 MB
  u16* kb = qb + (size_t)NSEQ * DIMK;      // 16 MB

  const int total8 = (NSEQ * DIMK + 2 * DIMK * DIMK) / 8;
  cast3_f32_bf16<<<total8 / 256, 256, 0, stream>>>(x, Wq, Wk, xb, wqb, wkb);

  gemm_qk<<<dim3(DIMK / 256, NSEQ / 256, 2), 512, 0, stream>>>(xb, wqb, wkb,
                                                               bq, bk, qb, kb);

  const float scale = 1.0f / sqrtf((float)DIMK);
  gemm_scores<<<dim3(NSEQ / 256, NSEQ / 256, 1), 512, 0, stream>>>(qb, kb, out,
                                                                   scale);
}